// Round 2
// baseline (1169.069 us; speedup 1.0000x reference)
//
#include <hip/hip_runtime.h>
#include <hip/hip_bf16.h>

typedef __attribute__((ext_vector_type(4))) float f32x4;
typedef __attribute__((ext_vector_type(8))) __bf16 bf16x8;

#define SDIM 2048
#define DDIM 512
#define HH 8
#define DH 64

// ---- LayerNorm(q) -> bf16 qn [4096][512], one wave per row
__global__ __launch_bounds__(256) void ln_kernel(const float* __restrict__ q,
                                                 const float* __restrict__ gamma,
                                                 const float* __restrict__ beta,
                                                 __bf16* __restrict__ qn) {
  int row = blockIdx.x * 4 + (threadIdx.x >> 6);
  int lane = threadIdx.x & 63;
  const float* qr = q + (size_t)row * DDIM + lane * 8;
  f32x4 x0 = *(const f32x4*)qr;
  f32x4 x1 = *(const f32x4*)(qr + 4);
  float s = 0.f;
#pragma unroll
  for (int i = 0; i < 4; ++i) s += x0[i] + x1[i];
#pragma unroll
  for (int off = 32; off; off >>= 1) s += __shfl_xor(s, off);
  float mu = s * (1.f / DDIM);
  float vs = 0.f;
#pragma unroll
  for (int i = 0; i < 4; ++i) {
    float d0 = x0[i] - mu, d1 = x1[i] - mu;
    vs += d0 * d0 + d1 * d1;
  }
#pragma unroll
  for (int off = 32; off; off >>= 1) vs += __shfl_xor(vs, off);
  float inv = rsqrtf(vs * (1.f / DDIM) + 1e-6f);
  const float* g = gamma + lane * 8;
  const float* be = beta + lane * 8;
  bf16x8 o;
#pragma unroll
  for (int i = 0; i < 8; ++i) {
    float xv = (i < 4) ? x0[i] : x1[i - 4];
    o[i] = (__bf16)((xv - mu) * inv * g[i] + be[i]);
  }
  *(bf16x8*)(qn + (size_t)row * DDIM + lane * 8) = o;
}

// ---- projections (SCALAR): qh[b,h,s,dk] (scaled 1/(8*(lam+1))), kh[b,h,s,dk], vT[b,h,dv,s]
// Same grid/block/epilogue as the MFMA version; inner product done in f32 VALU.
__global__ __launch_bounds__(256) void proj_scalar(const __bf16* __restrict__ qn,
                                                   const float* __restrict__ kin,
                                                   const float* __restrict__ vin,
                                                   const float* __restrict__ w_q,
                                                   const float* __restrict__ w_k,
                                                   const float* __restrict__ w_v,
                                                   const float* __restrict__ lam,
                                                   __bf16* __restrict__ qh,
                                                   __bf16* __restrict__ kh,
                                                   __bf16* __restrict__ vT) {
  int which = blockIdx.z;
  int n0 = blockIdx.x * 64;
  int m0 = blockIdx.y * 64;
  int wid = threadIdx.x >> 6, lane = threadIdx.x & 63;
  int lr = lane & 15, lg = lane >> 4;
  int mrow = m0 + wid * 16 + lg * 4;  // this thread's first output row
  const float* W = which == 0 ? w_q : which == 1 ? w_k : w_v;
  float acc[4][4] = {};  // [c][r]
  for (int k = 0; k < DDIM; k += 8) {
    float a[4][8];
    if (which == 0) {
#pragma unroll
      for (int r = 0; r < 4; ++r) {
        bf16x8 v8 = *(const bf16x8*)(qn + (size_t)(mrow + r) * DDIM + k);
#pragma unroll
        for (int j = 0; j < 8; ++j) a[r][j] = (float)v8[j];
      }
    } else {
      const float* A = which == 1 ? kin : vin;
#pragma unroll
      for (int r = 0; r < 4; ++r) {
        f32x4 y0 = *(const f32x4*)(A + (size_t)(mrow + r) * DDIM + k);
        f32x4 y1 = *(const f32x4*)(A + (size_t)(mrow + r) * DDIM + k + 4);
#pragma unroll
        for (int j = 0; j < 4; ++j) { a[r][j] = y0[j]; a[r][j + 4] = y1[j]; }
      }
    }
#pragma unroll
    for (int j = 0; j < 8; ++j) {
#pragma unroll
      for (int c = 0; c < 4; ++c) {
        float wv = W[(size_t)(k + j) * DDIM + n0 + c * 16 + lr];
#pragma unroll
        for (int r = 0; r < 4; ++r) acc[c][r] += a[r][j] * wv;
      }
    }
  }
#pragma unroll
  for (int c = 0; c < 4; ++c) {
#pragma unroll
    for (int r = 0; r < 4; ++r) {
      int m = mrow + r;
      int n = n0 + c * 16 + lr;
      int b = m >> 11, ss = m & 2047;
      int h = n >> 6, dd = n & 63;
      float val = acc[c][r];
      size_t hoff = (size_t)(b * HH + h) * SDIM + ss;
      if (which == 0) {
        float sc = 1.f / (8.f * (lam[h] + 1.f));
        qh[hoff * DH + dd] = (__bf16)(val * sc);
      } else if (which == 1) {
        kh[hoff * DH + dd] = (__bf16)val;
      } else {
        vT[((size_t)(b * HH + h) * DH + dd) * SDIM + ss] = (__bf16)val;
      }
    }
  }
}

// ---- fused scores + blend + mask + softmax (SCALAR inner product), writes attn f32
// Identical grid/block/epilogue to the MFMA version; acc[c][r] has the same meaning.
__global__ __launch_bounds__(512) void scores_scalar(const __bf16* __restrict__ qh,
                                                     const __bf16* __restrict__ kh,
                                                     const float* __restrict__ static_cov,
                                                     const int* __restrict__ mask,
                                                     const float* __restrict__ lam,
                                                     float* __restrict__ attn) {
  int bh = blockIdx.x;
  int q0 = blockIdx.y * 16;
  int b = bh >> 3, h = bh & 7;
  int wid = threadIdx.x >> 6, lane = threadIdx.x & 63;
  int lr = lane & 15, lg = lane >> 4;
  int col0 = wid * 256;
  float acc[16][4];
#pragma unroll
  for (int c = 0; c < 16; ++c)
#pragma unroll
    for (int r = 0; r < 4; ++r) acc[c][r] = 0.f;
  const __bf16* qbase = qh + ((size_t)bh * SDIM + q0 + lg * 4) * DH;
  const __bf16* kbase = kh + ((size_t)bh * SDIM + col0 + lr) * DH;
  for (int k = 0; k < DH; k += 8) {
    float qv[4][8];
#pragma unroll
    for (int r = 0; r < 4; ++r) {
      bf16x8 v8 = *(const bf16x8*)(qbase + (size_t)r * DH + k);
#pragma unroll
      for (int j = 0; j < 8; ++j) qv[r][j] = (float)v8[j];
    }
#pragma unroll
    for (int c = 0; c < 16; ++c) {
      bf16x8 kv = *(const bf16x8*)(kbase + (size_t)c * 16 * DH + k);
#pragma unroll
      for (int j = 0; j < 8; ++j) {
        float kf = (float)kv[j];
#pragma unroll
        for (int r = 0; r < 4; ++r) acc[c][r] += qv[r][j] * kf;
      }
    }
  }
  float blend = lam[h] / (lam[h] + 1.f);
  float mx[4] = {-3.4e38f, -3.4e38f, -3.4e38f, -3.4e38f};
  const float* srow = static_cov + ((size_t)b * SDIM + q0) * SDIM;
  const int* mkrow = mask + ((size_t)b * SDIM + q0) * SDIM;
#pragma unroll
  for (int c = 0; c < 16; ++c) {
    int gcol = col0 + c * 16 + lr;
#pragma unroll
    for (int r = 0; r < 4; ++r) {
      int lrow = lg * 4 + r;
      size_t idx = (size_t)lrow * SDIM + gcol;
      float valv = acc[c][r] + blend * srow[idx];
      valv = (mkrow[idx] == 0) ? -1e9f : valv;
      acc[c][r] = valv;
      mx[r] = fmaxf(mx[r], valv);
    }
  }
#pragma unroll
  for (int r = 0; r < 4; ++r) {
#pragma unroll
    for (int off = 1; off < 16; off <<= 1) mx[r] = fmaxf(mx[r], __shfl_xor(mx[r], off));
  }
  __shared__ float wred[8][16];
  __shared__ float fred[16];
  if (lr == 0) {
#pragma unroll
    for (int r = 0; r < 4; ++r) wred[wid][lg * 4 + r] = mx[r];
  }
  __syncthreads();
  if (threadIdx.x < 16) {
    float mm = wred[0][threadIdx.x];
#pragma unroll
    for (int w = 1; w < 8; ++w) mm = fmaxf(mm, wred[w][threadIdx.x]);
    fred[threadIdx.x] = mm;
  }
  __syncthreads();
  float fm[4], sm[4] = {0.f, 0.f, 0.f, 0.f};
#pragma unroll
  for (int r = 0; r < 4; ++r) fm[r] = fred[lg * 4 + r];
#pragma unroll
  for (int c = 0; c < 16; ++c) {
#pragma unroll
    for (int r = 0; r < 4; ++r) {
      float p = __expf(acc[c][r] - fm[r]);
      acc[c][r] = p;
      sm[r] += p;
    }
  }
#pragma unroll
  for (int r = 0; r < 4; ++r) {
#pragma unroll
    for (int off = 1; off < 16; off <<= 1) sm[r] += __shfl_xor(sm[r], off);
  }
  __syncthreads();
  if (lr == 0) {
#pragma unroll
    for (int r = 0; r < 4; ++r) wred[wid][lg * 4 + r] = sm[r];
  }
  __syncthreads();
  if (threadIdx.x < 16) {
    float ssum = 0.f;
#pragma unroll
    for (int w = 0; w < 8; ++w) ssum += wred[w][threadIdx.x];
    fred[threadIdx.x] = 1.f / ssum;
  }
  __syncthreads();
  float inv[4];
#pragma unroll
  for (int r = 0; r < 4; ++r) inv[r] = fred[lg * 4 + r];
  float* abase = attn + ((size_t)bh * SDIM + q0) * SDIM;
#pragma unroll
  for (int c = 0; c < 16; ++c) {
#pragma unroll
    for (int r = 0; r < 4; ++r) {
      abase[(size_t)(lg * 4 + r) * SDIM + col0 + c * 16 + lr] = acc[c][r] * inv[r];
    }
  }
}

// ---- PV (SCALAR): oh[m][h*64+d] = attn @ vh ; same grid/block/epilogue as MFMA version
__global__ __launch_bounds__(256) void pv_scalar(const float* __restrict__ attn,
                                                 const __bf16* __restrict__ vT,
                                                 __bf16* __restrict__ oh) {
  int bh = blockIdx.x;
  int q0 = blockIdx.y * 16;
  int wid = threadIdx.x >> 6, lane = threadIdx.x & 63;
  int lr = lane & 15, lg = lane >> 4;
  float acc[4][4] = {};
  const float* abase2 = attn + ((size_t)bh * SDIM + q0 + lg * 4) * SDIM;
  const __bf16* vbase = vT + ((size_t)bh * DH + lr) * SDIM;
  for (int kb = wid * 512; kb < wid * 512 + 512; kb += 8) {
    float av[4][8];
#pragma unroll
    for (int r = 0; r < 4; ++r) {
      f32x4 y0 = *(const f32x4*)(abase2 + (size_t)r * SDIM + kb);
      f32x4 y1 = *(const f32x4*)(abase2 + (size_t)r * SDIM + kb + 4);
#pragma unroll
      for (int j = 0; j < 4; ++j) { av[r][j] = y0[j]; av[r][j + 4] = y1[j]; }
    }
#pragma unroll
    for (int c = 0; c < 4; ++c) {
      bf16x8 vv = *(const bf16x8*)(vbase + (size_t)c * 16 * SDIM + kb);
#pragma unroll
      for (int j = 0; j < 8; ++j) {
        float vf = (float)vv[j];
#pragma unroll
        for (int r = 0; r < 4; ++r) acc[c][r] += av[r][j] * vf;
      }
    }
  }
  __shared__ float part[4][16][64];
#pragma unroll
  for (int c = 0; c < 4; ++c)
#pragma unroll
    for (int r = 0; r < 4; ++r)
      part[wid][lg * 4 + r][c * 16 + lr] = acc[c][r];
  __syncthreads();
  int b = bh >> 3, h = bh & 7;
#pragma unroll
  for (int e = 0; e < 4; ++e) {
    int idx = threadIdx.x * 4 + e;
    int row = idx >> 6, col = idx & 63;
    float sv = part[0][row][col] + part[1][row][col] + part[2][row][col] + part[3][row][col];
    oh[((size_t)b * SDIM + q0 + row) * DDIM + h * DH + col] = (__bf16)sv;
  }
}

// ---- FC + residual (SCALAR): out = oh @ w_fc + q  (f32 out)
__global__ __launch_bounds__(256) void fc_scalar(const __bf16* __restrict__ oh,
                                                 const float* __restrict__ w_fc,
                                                 const float* __restrict__ resid,
                                                 float* __restrict__ out) {
  int n0 = blockIdx.x * 64;
  int m0 = blockIdx.y * 64;
  int wid = threadIdx.x >> 6, lane = threadIdx.x & 63;
  int lr = lane & 15, lg = lane >> 4;
  int mrow = m0 + wid * 16 + lg * 4;
  float acc[4][4] = {};
  for (int k = 0; k < DDIM; k += 8) {
    float a[4][8];
#pragma unroll
    for (int r = 0; r < 4; ++r) {
      bf16x8 v8 = *(const bf16x8*)(oh + (size_t)(mrow + r) * DDIM + k);
#pragma unroll
      for (int j = 0; j < 8; ++j) a[r][j] = (float)v8[j];
    }
#pragma unroll
    for (int j = 0; j < 8; ++j) {
#pragma unroll
      for (int c = 0; c < 4; ++c) {
        float wv = w_fc[(size_t)(k + j) * DDIM + n0 + c * 16 + lr];
#pragma unroll
        for (int r = 0; r < 4; ++r) acc[c][r] += a[r][j] * wv;
      }
    }
  }
#pragma unroll
  for (int c = 0; c < 4; ++c)
#pragma unroll
    for (int r = 0; r < 4; ++r) {
      size_t m = mrow + r;
      size_t n = n0 + c * 16 + lr;
      out[m * DDIM + n] = acc[c][r] + resid[m * DDIM + n];
    }
}

extern "C" void kernel_launch(void* const* d_in, const int* in_sizes, int n_in,
                              void* d_out, int out_size, void* d_ws, size_t ws_size,
                              hipStream_t stream) {
  const float* q = (const float*)d_in[0];
  const float* k = (const float*)d_in[1];
  const float* v = (const float*)d_in[2];
  const float* static_cov = (const float*)d_in[3];
  const int* mask = (const int*)d_in[4];
  const float* w_q = (const float*)d_in[5];
  const float* w_k = (const float*)d_in[6];
  const float* w_v = (const float*)d_in[7];
  const float* w_fc = (const float*)d_in[8];
  const float* lam = (const float*)d_in[9];
  const float* gamma = (const float*)d_in[10];
  const float* beta = (const float*)d_in[11];

  float* out = (float*)d_out;
  float* attn = out + (size_t)2 * SDIM * DDIM;

  char* ws = (char*)d_ws;
  const size_t MB4 = (size_t)4 << 20;
  __bf16* qn = (__bf16*)(ws);
  __bf16* qh = (__bf16*)(ws + 1 * MB4);
  __bf16* kh = (__bf16*)(ws + 2 * MB4);
  __bf16* vT = (__bf16*)(ws + 3 * MB4);
  __bf16* oh = (__bf16*)(ws + 4 * MB4);

  ln_kernel<<<dim3(1024), dim3(256), 0, stream>>>(q, gamma, beta, qn);
  proj_scalar<<<dim3(8, 64, 3), dim3(256), 0, stream>>>(qn, k, v, w_q, w_k, w_v, lam, qh, kh, vT);
  scores_scalar<<<dim3(16, 128), dim3(512), 0, stream>>>(qh, kh, static_cov, mask, lam, attn);
  pv_scalar<<<dim3(16, 128), dim3(256), 0, stream>>>(attn, vT, oh);
  fc_scalar<<<dim3(8, 64), dim3(256), 0, stream>>>(oh, vT == nullptr ? nullptr : w_fc, q, out);
}

// Round 3
// 400.437 us; speedup vs baseline: 2.9195x; 2.9195x over previous
//
#include <hip/hip_runtime.h>
#include <hip/hip_bf16.h>

typedef __attribute__((ext_vector_type(4))) float f32x4;
typedef __attribute__((ext_vector_type(8))) __bf16 bf16x8;

#define SDIM 2048
#define DDIM 512
#define HH 8
#define DH 64

static __device__ __forceinline__ f32x4 mfma_raw(bf16x8 a, bf16x8 b, f32x4 c) {
  return __builtin_amdgcn_mfma_f32_16x16x32_bf16(a, b, c, 0, 0, 0);
}

// Operand-order-corrected MFMA: under either hardware convention, makes
// acc[c][r] mean D[row = lg*4+r][col = lr] with row from Q/attn-side, col from K/W-side.
template <bool C1>
static __device__ __forceinline__ f32x4 mf(bf16x8 a, bf16x8 b, f32x4 c) {
  return C1 ? mfma_raw(a, b, c) : mfma_raw(b, a, c);
}

// ---- probe: decode the MFMA output-orientation convention at runtime
__global__ void mfma_probe(int* flag) {
  int lane = threadIdx.x & 63;
  float av = (float)(lane & 15);
  float bv = av * av;
  bf16x8 a, b;
#pragma unroll
  for (int i = 0; i < 8; ++i) { a[i] = (__bf16)av; b[i] = (__bf16)bv; }
  f32x4 d = {};
  d = mfma_raw(a, b, d);
  // conv-1 (first operand -> row=(l>>4)*4+r, second -> col=l&15):
  //   slot(lane17,r0): row=4 (a-val 4), col=1 (b-val 1) -> 32*4*1 = 128
  // conv-2 (first operand -> row=l&15, second -> col=(l>>4)*4+r):
  //   slot(lane17,r0): m=1 (a-val 1), n=4 (b-val 16) -> 32*1*16 = 512
  if (threadIdx.x == 17) *flag = (d[0] == 128.0f) ? 1 : 2;
}

// ---- LayerNorm(q) -> bf16 qn [4096][512], one wave per row
__global__ __launch_bounds__(256) void ln_kernel(const float* __restrict__ q,
                                                 const float* __restrict__ gamma,
                                                 const float* __restrict__ beta,
                                                 __bf16* __restrict__ qn) {
  int row = blockIdx.x * 4 + (threadIdx.x >> 6);
  int lane = threadIdx.x & 63;
  const float* qr = q + (size_t)row * DDIM + lane * 8;
  f32x4 x0 = *(const f32x4*)qr;
  f32x4 x1 = *(const f32x4*)(qr + 4);
  float s = 0.f;
#pragma unroll
  for (int i = 0; i < 4; ++i) s += x0[i] + x1[i];
#pragma unroll
  for (int off = 32; off; off >>= 1) s += __shfl_xor(s, off);
  float mu = s * (1.f / DDIM);
  float vs = 0.f;
#pragma unroll
  for (int i = 0; i < 4; ++i) {
    float d0 = x0[i] - mu, d1 = x1[i] - mu;
    vs += d0 * d0 + d1 * d1;
  }
#pragma unroll
  for (int off = 32; off; off >>= 1) vs += __shfl_xor(vs, off);
  float inv = rsqrtf(vs * (1.f / DDIM) + 1e-6f);
  const float* g = gamma + lane * 8;
  const float* be = beta + lane * 8;
  bf16x8 o;
#pragma unroll
  for (int i = 0; i < 8; ++i) {
    float xv = (i < 4) ? x0[i] : x1[i - 4];
    o[i] = (__bf16)((xv - mu) * inv * g[i] + be[i]);
  }
  *(bf16x8*)(qn + (size_t)row * DDIM + lane * 8) = o;
}

// ---- cast+transpose weights: t[n*512+k] = (bf16)W[k*512+n]
__global__ __launch_bounds__(256) void wtrans_kernel(const float* __restrict__ w0,
                                                     const float* __restrict__ w1,
                                                     const float* __restrict__ w2,
                                                     const float* __restrict__ w3,
                                                     __bf16* __restrict__ t0,
                                                     __bf16* __restrict__ t1,
                                                     __bf16* __restrict__ t2,
                                                     __bf16* __restrict__ t3) {
  const float* w = blockIdx.y == 0 ? w0 : blockIdx.y == 1 ? w1 : blockIdx.y == 2 ? w2 : w3;
  __bf16* t = blockIdx.y == 0 ? t0 : blockIdx.y == 1 ? t1 : blockIdx.y == 2 ? t2 : t3;
  int oidx = blockIdx.x * 256 + threadIdx.x;
  int n = oidx >> 9, kk = oidx & 511;
  t[oidx] = (__bf16)w[(size_t)kk * DDIM + n];
}

// ---- projections: qh[b,h,s,dk] (scaled 1/(8*(lam+1))), kh[b,h,s,dk], vT[b,h,dv,s]
template <bool C1>
static __device__ __forceinline__ void proj_body(const __bf16* __restrict__ qn,
                                                 const float* __restrict__ kin,
                                                 const float* __restrict__ vin,
                                                 const __bf16* __restrict__ wqT,
                                                 const __bf16* __restrict__ wkT,
                                                 const __bf16* __restrict__ wvT,
                                                 const float* __restrict__ lam,
                                                 __bf16* __restrict__ qh,
                                                 __bf16* __restrict__ kh,
                                                 __bf16* __restrict__ vT) {
  int which = blockIdx.z;
  int n0 = blockIdx.x * 64;
  int m0 = blockIdx.y * 64;
  int wid = threadIdx.x >> 6, lane = threadIdx.x & 63;
  int lr = lane & 15, lg = lane >> 4;
  int mrow = m0 + wid * 16;
  const __bf16* wT = which == 0 ? wqT : which == 1 ? wkT : wvT;
  f32x4 acc[4] = {};
  for (int kb = 0; kb < DDIM; kb += 32) {
    bf16x8 afrag;
    if (which == 0) {
      afrag = *(const bf16x8*)(qn + (size_t)(mrow + lr) * DDIM + kb + lg * 8);
    } else {
      const float* src = (which == 1 ? kin : vin) + (size_t)(mrow + lr) * DDIM + kb + lg * 8;
      f32x4 y0 = *(const f32x4*)src;
      f32x4 y1 = *(const f32x4*)(src + 4);
#pragma unroll
      for (int i = 0; i < 4; ++i) { afrag[i] = (__bf16)y0[i]; afrag[i + 4] = (__bf16)y1[i]; }
    }
#pragma unroll
    for (int c = 0; c < 4; ++c) {
      bf16x8 bfrag = *(const bf16x8*)(wT + (size_t)(n0 + c * 16 + lr) * DDIM + kb + lg * 8);
      acc[c] = mf<C1>(afrag, bfrag, acc[c]);
    }
  }
#pragma unroll
  for (int c = 0; c < 4; ++c) {
#pragma unroll
    for (int r = 0; r < 4; ++r) {
      int m = mrow + lg * 4 + r;
      int n = n0 + c * 16 + lr;
      int b = m >> 11, ss = m & 2047;
      int h = n >> 6, dd = n & 63;
      float val = acc[c][r];
      size_t hoff = (size_t)(b * HH + h) * SDIM + ss;
      if (which == 0) {
        float sc = 1.f / (8.f * (lam[h] + 1.f));
        qh[hoff * DH + dd] = (__bf16)(val * sc);
      } else if (which == 1) {
        kh[hoff * DH + dd] = (__bf16)val;
      } else {
        vT[((size_t)(b * HH + h) * DH + dd) * SDIM + ss] = (__bf16)val;
      }
    }
  }
}

__global__ __launch_bounds__(256) void proj_kernel(const __bf16* __restrict__ qn,
                                                   const float* __restrict__ kin,
                                                   const float* __restrict__ vin,
                                                   const __bf16* __restrict__ wqT,
                                                   const __bf16* __restrict__ wkT,
                                                   const __bf16* __restrict__ wvT,
                                                   const float* __restrict__ lam,
                                                   __bf16* __restrict__ qh,
                                                   __bf16* __restrict__ kh,
                                                   __bf16* __restrict__ vT,
                                                   const int* __restrict__ flag) {
  if (*flag == 1) proj_body<true>(qn, kin, vin, wqT, wkT, wvT, lam, qh, kh, vT);
  else            proj_body<false>(qn, kin, vin, wqT, wkT, wvT, lam, qh, kh, vT);
}

// ---- fused scores + blend + mask + softmax, writes attn [b,h,s,s] f32
template <bool C1>
static __device__ __forceinline__ void scores_body(const __bf16* __restrict__ qh,
                                                   const __bf16* __restrict__ kh,
                                                   const float* __restrict__ static_cov,
                                                   const int* __restrict__ mask,
                                                   const float* __restrict__ lam,
                                                   float* __restrict__ attn) {
  int bh = blockIdx.x;
  int q0 = blockIdx.y * 16;
  int b = bh >> 3, h = bh & 7;
  int wid = threadIdx.x >> 6, lane = threadIdx.x & 63;
  int lr = lane & 15, lg = lane >> 4;
  int col0 = wid * 256;
  const __bf16* qbase = qh + ((size_t)bh * SDIM + q0) * DH;
  const __bf16* kbase = kh + (size_t)bh * SDIM * DH;
  bf16x8 a0 = *(const bf16x8*)(qbase + lr * DH + lg * 8);
  bf16x8 a1 = *(const bf16x8*)(qbase + lr * DH + 32 + lg * 8);
  f32x4 acc[16];
#pragma unroll
  for (int c = 0; c < 16; ++c) {
    const __bf16* kp = kbase + (size_t)(col0 + c * 16 + lr) * DH + lg * 8;
    bf16x8 b0 = *(const bf16x8*)kp;
    bf16x8 b1 = *(const bf16x8*)(kp + 32);
    f32x4 t = {};
    t = mf<C1>(a0, b0, t);
    t = mf<C1>(a1, b1, t);
    acc[c] = t;
  }
  float blend = lam[h] / (lam[h] + 1.f);
  float mx[4] = {-3.4e38f, -3.4e38f, -3.4e38f, -3.4e38f};
  const float* srow = static_cov + ((size_t)b * SDIM + q0) * SDIM;
  const int* mkrow = mask + ((size_t)b * SDIM + q0) * SDIM;
#pragma unroll
  for (int c = 0; c < 16; ++c) {
    int gcol = col0 + c * 16 + lr;
#pragma unroll
    for (int r = 0; r < 4; ++r) {
      int lrow = lg * 4 + r;
      size_t idx = (size_t)lrow * SDIM + gcol;
      float valv = acc[c][r] + blend * srow[idx];
      valv = (mkrow[idx] == 0) ? -1e9f : valv;
      acc[c][r] = valv;
      mx[r] = fmaxf(mx[r], valv);
    }
  }
#pragma unroll
  for (int r = 0; r < 4; ++r) {
#pragma unroll
    for (int off = 1; off < 16; off <<= 1) mx[r] = fmaxf(mx[r], __shfl_xor(mx[r], off));
  }
  __shared__ float wred[8][16];
  __shared__ float fred[16];
  if (lr == 0) {
#pragma unroll
    for (int r = 0; r < 4; ++r) wred[wid][lg * 4 + r] = mx[r];
  }
  __syncthreads();
  if (threadIdx.x < 16) {
    float mm = wred[0][threadIdx.x];
#pragma unroll
    for (int w = 1; w < 8; ++w) mm = fmaxf(mm, wred[w][threadIdx.x]);
    fred[threadIdx.x] = mm;
  }
  __syncthreads();
  float fm[4], sm[4] = {0.f, 0.f, 0.f, 0.f};
#pragma unroll
  for (int r = 0; r < 4; ++r) fm[r] = fred[lg * 4 + r];
#pragma unroll
  for (int c = 0; c < 16; ++c) {
#pragma unroll
    for (int r = 0; r < 4; ++r) {
      float p = __expf(acc[c][r] - fm[r]);
      acc[c][r] = p;
      sm[r] += p;
    }
  }
#pragma unroll
  for (int r = 0; r < 4; ++r) {
#pragma unroll
    for (int off = 1; off < 16; off <<= 1) sm[r] += __shfl_xor(sm[r], off);
  }
  __syncthreads();
  if (lr == 0) {
#pragma unroll
    for (int r = 0; r < 4; ++r) wred[wid][lg * 4 + r] = sm[r];
  }
  __syncthreads();
  if (threadIdx.x < 16) {
    float ssum = 0.f;
#pragma unroll
    for (int w = 0; w < 8; ++w) ssum += wred[w][threadIdx.x];
    fred[threadIdx.x] = 1.f / ssum;
  }
  __syncthreads();
  float inv[4];
#pragma unroll
  for (int r = 0; r < 4; ++r) inv[r] = fred[lg * 4 + r];
  float* abase = attn + ((size_t)bh * SDIM + q0) * SDIM;
#pragma unroll
  for (int c = 0; c < 16; ++c) {
#pragma unroll
    for (int r = 0; r < 4; ++r) {
      abase[(size_t)(lg * 4 + r) * SDIM + col0 + c * 16 + lr] = acc[c][r] * inv[r];
    }
  }
}

__global__ __launch_bounds__(512) void scores_kernel(const __bf16* __restrict__ qh,
                                                     const __bf16* __restrict__ kh,
                                                     const float* __restrict__ static_cov,
                                                     const int* __restrict__ mask,
                                                     const float* __restrict__ lam,
                                                     float* __restrict__ attn,
                                                     const int* __restrict__ flag) {
  if (*flag == 1) scores_body<true>(qh, kh, static_cov, mask, lam, attn);
  else            scores_body<false>(qh, kh, static_cov, mask, lam, attn);
}

// ---- PV: oh[m][h*64+d] (bf16) = attn @ vh ; block = 16 q-rows, 4 waves split K
template <bool C1>
static __device__ __forceinline__ void pv_body(const float* __restrict__ attn,
                                               const __bf16* __restrict__ vT,
                                               __bf16* __restrict__ oh) {
  int bh = blockIdx.x;
  int q0 = blockIdx.y * 16;
  int wid = threadIdx.x >> 6, lane = threadIdx.x & 63;
  int lr = lane & 15, lg = lane >> 4;
  const float* arow = attn + ((size_t)bh * SDIM + q0) * SDIM;
  const __bf16* vbase = vT + (size_t)bh * DH * SDIM;
  f32x4 acc[4] = {};
  for (int kb = wid * 512; kb < wid * 512 + 512; kb += 32) {
    const float* ap = arow + (size_t)lr * SDIM + kb + lg * 8;
    f32x4 y0 = *(const f32x4*)ap;
    f32x4 y1 = *(const f32x4*)(ap + 4);
    bf16x8 afrag;
#pragma unroll
    for (int i = 0; i < 4; ++i) { afrag[i] = (__bf16)y0[i]; afrag[i + 4] = (__bf16)y1[i]; }
#pragma unroll
    for (int c = 0; c < 4; ++c) {
      bf16x8 bfrag = *(const bf16x8*)(vbase + (size_t)(c * 16 + lr) * SDIM + kb + lg * 8);
      acc[c] = mf<C1>(afrag, bfrag, acc[c]);
    }
  }
  __shared__ float part[4][16][64];
#pragma unroll
  for (int c = 0; c < 4; ++c)
#pragma unroll
    for (int r = 0; r < 4; ++r)
      part[wid][lg * 4 + r][c * 16 + lr] = acc[c][r];
  __syncthreads();
  int b = bh >> 3, h = bh & 7;
#pragma unroll
  for (int e = 0; e < 4; ++e) {
    int idx = threadIdx.x * 4 + e;
    int row = idx >> 6, col = idx & 63;
    float sv = part[0][row][col] + part[1][row][col] + part[2][row][col] + part[3][row][col];
    oh[((size_t)b * SDIM + q0 + row) * DDIM + h * DH + col] = (__bf16)sv;
  }
}

__global__ __launch_bounds__(256) void pv_kernel(const float* __restrict__ attn,
                                                 const __bf16* __restrict__ vT,
                                                 __bf16* __restrict__ oh,
                                                 const int* __restrict__ flag) {
  if (*flag == 1) pv_body<true>(attn, vT, oh);
  else            pv_body<false>(attn, vT, oh);
}

// ---- FC + residual: out = oh @ w_fc + q  (f32 out)
template <bool C1>
static __device__ __forceinline__ void fc_body(const __bf16* __restrict__ oh,
                                               const __bf16* __restrict__ wfcT,
                                               const float* __restrict__ resid,
                                               float* __restrict__ out) {
  int n0 = blockIdx.x * 64;
  int m0 = blockIdx.y * 64;
  int wid = threadIdx.x >> 6, lane = threadIdx.x & 63;
  int lr = lane & 15, lg = lane >> 4;
  int mrow = m0 + wid * 16;
  f32x4 acc[4] = {};
  for (int kb = 0; kb < DDIM; kb += 32) {
    bf16x8 afrag = *(const bf16x8*)(oh + (size_t)(mrow + lr) * DDIM + kb + lg * 8);
#pragma unroll
    for (int c = 0; c < 4; ++c) {
      bf16x8 bfrag = *(const bf16x8*)(wfcT + (size_t)(n0 + c * 16 + lr) * DDIM + kb + lg * 8);
      acc[c] = mf<C1>(afrag, bfrag, acc[c]);
    }
  }
#pragma unroll
  for (int c = 0; c < 4; ++c)
#pragma unroll
    for (int r = 0; r < 4; ++r) {
      size_t m = mrow + lg * 4 + r;
      size_t n = n0 + c * 16 + lr;
      out[m * DDIM + n] = acc[c][r] + resid[m * DDIM + n];
    }
}

__global__ __launch_bounds__(256) void fc_kernel(const __bf16* __restrict__ oh,
                                                 const __bf16* __restrict__ wfcT,
                                                 const float* __restrict__ resid,
                                                 float* __restrict__ out,
                                                 const int* __restrict__ flag) {
  if (*flag == 1) fc_body<true>(oh, wfcT, resid, out);
  else            fc_body<false>(oh, wfcT, resid, out);
}

extern "C" void kernel_launch(void* const* d_in, const int* in_sizes, int n_in,
                              void* d_out, int out_size, void* d_ws, size_t ws_size,
                              hipStream_t stream) {
  const float* q = (const float*)d_in[0];
  const float* k = (const float*)d_in[1];
  const float* v = (const float*)d_in[2];
  const float* static_cov = (const float*)d_in[3];
  const int* mask = (const int*)d_in[4];
  const float* w_q = (const float*)d_in[5];
  const float* w_k = (const float*)d_in[6];
  const float* w_v = (const float*)d_in[7];
  const float* w_fc = (const float*)d_in[8];
  const float* lam = (const float*)d_in[9];
  const float* gamma = (const float*)d_in[10];
  const float* beta = (const float*)d_in[11];

  float* out = (float*)d_out;
  float* attn = out + (size_t)2 * SDIM * DDIM;

  char* ws = (char*)d_ws;
  const size_t MB4 = (size_t)4 << 20;
  __bf16* qn  = (__bf16*)(ws);
  __bf16* qh  = (__bf16*)(ws + 1 * MB4);
  __bf16* kh  = (__bf16*)(ws + 2 * MB4);
  __bf16* vT  = (__bf16*)(ws + 3 * MB4);
  __bf16* oh  = (__bf16*)(ws + 4 * MB4);
  __bf16* wqT = (__bf16*)(ws + 5 * MB4);
  __bf16* wkT = (__bf16*)(ws + 5 * MB4 + 524288);
  __bf16* wvT = (__bf16*)(ws + 5 * MB4 + 2 * 524288);
  __bf16* wfcT= (__bf16*)(ws + 5 * MB4 + 3 * 524288);
  int* flag   = (int*)(ws + 5 * MB4 + 4 * 524288);

  mfma_probe<<<dim3(1), dim3(64), 0, stream>>>(flag);
  ln_kernel<<<dim3(1024), dim3(256), 0, stream>>>(q, gamma, beta, qn);
  wtrans_kernel<<<dim3(1024, 4), dim3(256), 0, stream>>>(w_q, w_k, w_v, w_fc, wqT, wkT, wvT, wfcT);
  proj_kernel<<<dim3(8, 64, 3), dim3(256), 0, stream>>>(qn, k, v, wqT, wkT, wvT, lam, qh, kh, vT, flag);
  scores_kernel<<<dim3(16, 128), dim3(512), 0, stream>>>(qh, kh, static_cov, mask, lam, attn, flag);
  pv_kernel<<<dim3(16, 128), dim3(256), 0, stream>>>(attn, vT, oh, flag);
  fc_kernel<<<dim3(8, 64), dim3(256), 0, stream>>>(oh, wfcT, q, out, flag);
}

// Round 4
// 331.229 us; speedup vs baseline: 3.5295x; 1.2089x over previous
//
#include <hip/hip_runtime.h>
#include <hip/hip_bf16.h>

typedef __attribute__((ext_vector_type(4))) float f32x4;
typedef __attribute__((ext_vector_type(4))) int i32x4;
typedef __attribute__((ext_vector_type(4))) unsigned int u32x4;
typedef __attribute__((ext_vector_type(8))) __bf16 bf16x8;

#define SDIM 2048
#define DDIM 512
#define HH 8
#define DH 64

static __device__ __forceinline__ f32x4 mfma_raw(bf16x8 a, bf16x8 b, f32x4 c) {
  return __builtin_amdgcn_mfma_f32_16x16x32_bf16(a, b, c, 0, 0, 0);
}

// Operand-order-corrected MFMA: acc[c][r] = D[row = tile + lg*4 + r][col = lr],
// row side fed by FIRST logical operand under either hardware convention.
template <bool C1>
static __device__ __forceinline__ f32x4 mf(bf16x8 a, bf16x8 b, f32x4 c) {
  return C1 ? mfma_raw(a, b, c) : mfma_raw(b, a, c);
}

static __device__ __forceinline__ unsigned pack_bf16(float a, float b) {
  __bf16 x = (__bf16)a, y = (__bf16)b;
  unsigned short ux = __builtin_bit_cast(unsigned short, x);
  unsigned short uy = __builtin_bit_cast(unsigned short, y);
  return ((unsigned)uy << 16) | (unsigned)ux;
}

// ---- probe: decode the MFMA output-orientation convention at runtime
__global__ void mfma_probe(int* flag) {
  int lane = threadIdx.x & 63;
  float av = (float)(lane & 15);
  float bv = av * av;
  bf16x8 a, b;
#pragma unroll
  for (int i = 0; i < 8; ++i) { a[i] = (__bf16)av; b[i] = (__bf16)bv; }
  f32x4 d = {};
  d = mfma_raw(a, b, d);
  if (threadIdx.x == 17) *flag = (d[0] == 128.0f) ? 1 : 2;
}

// ---- LayerNorm(q) -> bf16 qn [4096][512], one wave per row
__global__ __launch_bounds__(256) void ln_kernel(const float* __restrict__ q,
                                                 const float* __restrict__ gamma,
                                                 const float* __restrict__ beta,
                                                 __bf16* __restrict__ qn) {
  int row = blockIdx.x * 4 + (threadIdx.x >> 6);
  int lane = threadIdx.x & 63;
  const float* qr = q + (size_t)row * DDIM + lane * 8;
  f32x4 x0 = *(const f32x4*)qr;
  f32x4 x1 = *(const f32x4*)(qr + 4);
  float s = 0.f;
#pragma unroll
  for (int i = 0; i < 4; ++i) s += x0[i] + x1[i];
#pragma unroll
  for (int off = 32; off; off >>= 1) s += __shfl_xor(s, off);
  float mu = s * (1.f / DDIM);
  float vs = 0.f;
#pragma unroll
  for (int i = 0; i < 4; ++i) {
    float d0 = x0[i] - mu, d1 = x1[i] - mu;
    vs += d0 * d0 + d1 * d1;
  }
#pragma unroll
  for (int off = 32; off; off >>= 1) vs += __shfl_xor(vs, off);
  float inv = rsqrtf(vs * (1.f / DDIM) + 1e-6f);
  const float* g = gamma + lane * 8;
  const float* be = beta + lane * 8;
  bf16x8 o;
#pragma unroll
  for (int i = 0; i < 8; ++i) {
    float xv = (i < 4) ? x0[i] : x1[i - 4];
    o[i] = (__bf16)((xv - mu) * inv * g[i] + be[i]);
  }
  *(bf16x8*)(qn + (size_t)row * DDIM + lane * 8) = o;
}

// ---- cast+transpose weights: t[n*512+k] = (bf16)W[k*512+n]
__global__ __launch_bounds__(256) void wtrans_kernel(const float* __restrict__ w0,
                                                     const float* __restrict__ w1,
                                                     const float* __restrict__ w2,
                                                     const float* __restrict__ w3,
                                                     __bf16* __restrict__ t0,
                                                     __bf16* __restrict__ t1,
                                                     __bf16* __restrict__ t2,
                                                     __bf16* __restrict__ t3) {
  const float* w = blockIdx.y == 0 ? w0 : blockIdx.y == 1 ? w1 : blockIdx.y == 2 ? w2 : w3;
  __bf16* t = blockIdx.y == 0 ? t0 : blockIdx.y == 1 ? t1 : blockIdx.y == 2 ? t2 : t3;
  int oidx = blockIdx.x * 256 + threadIdx.x;
  int n = oidx >> 9, kk = oidx & 511;
  t[oidx] = (__bf16)w[(size_t)kk * DDIM + n];
}

// ---- projections: qh[b,h,s,dk] (scaled 1/(8*(lam+1))), kh[b,h,s,dk], vT[b,h,dv,s]
template <bool C1>
static __device__ __forceinline__ void proj_body(const __bf16* __restrict__ qn,
                                                 const float* __restrict__ kin,
                                                 const float* __restrict__ vin,
                                                 const __bf16* __restrict__ wqT,
                                                 const __bf16* __restrict__ wkT,
                                                 const __bf16* __restrict__ wvT,
                                                 const float* __restrict__ lam,
                                                 __bf16* __restrict__ qh,
                                                 __bf16* __restrict__ kh,
                                                 __bf16* __restrict__ vT) {
  int which = blockIdx.z;
  int n0 = blockIdx.x * 64;
  int m0 = blockIdx.y * 64;
  int wid = threadIdx.x >> 6, lane = threadIdx.x & 63;
  int lr = lane & 15, lg = lane >> 4;
  int mrow = m0 + wid * 16;
  const __bf16* wT = which == 0 ? wqT : which == 1 ? wkT : wvT;
  f32x4 acc[4] = {};
  for (int kb = 0; kb < DDIM; kb += 32) {
    bf16x8 afrag;
    if (which == 0) {
      afrag = *(const bf16x8*)(qn + (size_t)(mrow + lr) * DDIM + kb + lg * 8);
    } else {
      const float* src = (which == 1 ? kin : vin) + (size_t)(mrow + lr) * DDIM + kb + lg * 8;
      f32x4 y0 = *(const f32x4*)src;
      f32x4 y1 = *(const f32x4*)(src + 4);
#pragma unroll
      for (int i = 0; i < 4; ++i) { afrag[i] = (__bf16)y0[i]; afrag[i + 4] = (__bf16)y1[i]; }
    }
#pragma unroll
    for (int c = 0; c < 4; ++c) {
      bf16x8 bfrag = *(const bf16x8*)(wT + (size_t)(n0 + c * 16 + lr) * DDIM + kb + lg * 8);
      acc[c] = mf<C1>(afrag, bfrag, acc[c]);
    }
  }
#pragma unroll
  for (int c = 0; c < 4; ++c) {
#pragma unroll
    for (int r = 0; r < 4; ++r) {
      int m = mrow + lg * 4 + r;
      int n = n0 + c * 16 + lr;
      int b = m >> 11, ss = m & 2047;
      int h = n >> 6, dd = n & 63;
      float val = acc[c][r];
      size_t hoff = (size_t)(b * HH + h) * SDIM + ss;
      if (which == 0) {
        float sc = 1.f / (8.f * (lam[h] + 1.f));
        qh[hoff * DH + dd] = (__bf16)(val * sc);
      } else if (which == 1) {
        kh[hoff * DH + dd] = (__bf16)val;
      } else {
        vT[((size_t)(b * HH + h) * DH + dd) * SDIM + ss] = (__bf16)val;
      }
    }
  }
}

__global__ __launch_bounds__(256) void proj_kernel(const __bf16* __restrict__ qn,
                                                   const float* __restrict__ kin,
                                                   const float* __restrict__ vin,
                                                   const __bf16* __restrict__ wqT,
                                                   const __bf16* __restrict__ wkT,
                                                   const __bf16* __restrict__ wvT,
                                                   const float* __restrict__ lam,
                                                   __bf16* __restrict__ qh,
                                                   __bf16* __restrict__ kh,
                                                   __bf16* __restrict__ vT,
                                                   const int* __restrict__ flag) {
  if (*flag == 1) proj_body<true>(qn, kin, vin, wqT, wkT, wvT, lam, qh, kh, vT);
  else            proj_body<false>(qn, kin, vin, wqT, wkT, wvT, lam, qh, kh, vT);
}

// ---- FUSED scores + blend + mask + softmax + attn write + PV + oh write
// block: 512 thr (8 waves); 16 q-rows x 2048 keys; wave w owns keys [w*256,(w+1)*256)
// Swapped layout: acc[c][r] = S[key = col0 + c*16 + lg*4 + r][q = lr]
template <bool C1>
static __device__ __forceinline__ void fused_body(const __bf16* __restrict__ qh,
                                                  const __bf16* __restrict__ kh,
                                                  const __bf16* __restrict__ vT,
                                                  const float* __restrict__ static_cov,
                                                  const int* __restrict__ mask,
                                                  const float* __restrict__ lam,
                                                  float* __restrict__ attn,
                                                  __bf16* __restrict__ oh) {
  int bh = blockIdx.x;
  int q0 = blockIdx.y * 16;
  int b = bh >> 3, h = bh & 7;
  int wid = threadIdx.x >> 6, lane = threadIdx.x & 63;
  int lr = lane & 15, lg = lane >> 4;
  int col0 = wid * 256;
  const __bf16* qbase = qh + ((size_t)bh * SDIM + q0) * DH;
  const __bf16* kbase = kh + (size_t)bh * SDIM * DH;
  // Q fragment (col side): lane needs Q[q=lr][k = lg*8+j]
  bf16x8 qf0 = *(const bf16x8*)(qbase + lr * DH + lg * 8);
  bf16x8 qf1 = *(const bf16x8*)(qbase + lr * DH + 32 + lg * 8);
  f32x4 acc[16];
#pragma unroll
  for (int c = 0; c < 16; ++c) {
    const __bf16* kp = kbase + (size_t)(col0 + c * 16 + lr) * DH + lg * 8;
    bf16x8 k0 = *(const bf16x8*)kp;
    bf16x8 k1 = *(const bf16x8*)(kp + 32);
    f32x4 t = {};
    t = mf<C1>(k0, qf0, t);   // row side = K (keys), col side = Q
    t = mf<C1>(k1, qf1, t);
    acc[c] = t;
  }
  float blend = lam[h] / (lam[h] + 1.f);
  const float* srow = static_cov + ((size_t)b * SDIM + q0 + lr) * SDIM + col0 + lg * 4;
  const int* mkrow = mask + ((size_t)b * SDIM + q0 + lr) * SDIM + col0 + lg * 4;
  float mx = -3.4e38f;
#pragma unroll
  for (int c = 0; c < 16; ++c) {
    f32x4 sc = *(const f32x4*)(srow + c * 16);
    i32x4 mk = *(const i32x4*)(mkrow + c * 16);
#pragma unroll
    for (int r = 0; r < 4; ++r) {
      float valv = acc[c][r] + blend * sc[r];
      valv = (mk[r] == 0) ? -1e9f : valv;
      acc[c][r] = valv;
      mx = fmaxf(mx, valv);
    }
  }
  mx = fmaxf(mx, __shfl_xor(mx, 16));
  mx = fmaxf(mx, __shfl_xor(mx, 32));
  __shared__ float wredm[8][16];
  __shared__ float wreds[8][16];
  __shared__ float fredm[16];
  __shared__ float freds[16];
  if (lg == 0) wredm[wid][lr] = mx;
  __syncthreads();
  if (threadIdx.x < 16) {
    float mm = wredm[0][threadIdx.x];
#pragma unroll
    for (int w = 1; w < 8; ++w) mm = fmaxf(mm, wredm[w][threadIdx.x]);
    fredm[threadIdx.x] = mm;
  }
  __syncthreads();
  float fm = fredm[lr];
  float sm = 0.f;
#pragma unroll
  for (int c = 0; c < 16; ++c) {
#pragma unroll
    for (int r = 0; r < 4; ++r) {
      float p = __expf(acc[c][r] - fm);
      acc[c][r] = p;
      sm += p;
    }
  }
  sm += __shfl_xor(sm, 16);
  sm += __shfl_xor(sm, 32);
  if (lg == 0) wreds[wid][lr] = sm;
  __syncthreads();
  if (threadIdx.x < 16) {
    float ssum = 0.f;
#pragma unroll
    for (int w = 0; w < 8; ++w) ssum += wreds[w][threadIdx.x];
    freds[threadIdx.x] = 1.f / ssum;
  }
  __syncthreads();
  float inv = freds[lr];
  // normalize, write attn (nontemporal, f32x4), pack bf16 words for PV
  float* abase = attn + ((size_t)bh * SDIM + q0 + lr) * SDIM + col0 + lg * 4;
  unsigned pw[16][2];
#pragma unroll
  for (int c = 0; c < 16; ++c) {
    f32x4 pn;
#pragma unroll
    for (int r = 0; r < 4; ++r) pn[r] = acc[c][r] * inv;
    __builtin_nontemporal_store(pn, (f32x4*)(abase + c * 16));
    pw[c][0] = pack_bf16(pn[0], pn[1]);
    pw[c][1] = pack_bf16(pn[2], pn[3]);
  }
  // ---- PV: O^T[dv][q] += V^T[dv][k] * P[q][k] over this wave's 256 keys
  const __bf16* vbase = vT + (size_t)bh * DH * SDIM + col0;
  int src0 = lr + 32 * (lg & 1);
  int src1 = src0 + 16;
  bool hi = (lg & 2) != 0;
  f32x4 oacc[4] = {};
#pragma unroll
  for (int t = 0; t < 8; ++t) {
    unsigned a0 = (unsigned)__shfl((int)pw[t * 2][0], src0);
    unsigned a1 = (unsigned)__shfl((int)pw[t * 2][1], src0);
    unsigned b0 = (unsigned)__shfl((int)pw[t * 2 + 1][0], src0);
    unsigned b1 = (unsigned)__shfl((int)pw[t * 2 + 1][1], src0);
    unsigned a2 = (unsigned)__shfl((int)pw[t * 2][0], src1);
    unsigned a3 = (unsigned)__shfl((int)pw[t * 2][1], src1);
    unsigned b2 = (unsigned)__shfl((int)pw[t * 2 + 1][0], src1);
    unsigned b3 = (unsigned)__shfl((int)pw[t * 2 + 1][1], src1);
    u32x4 wv;
    wv[0] = hi ? b0 : a0;
    wv[1] = hi ? b1 : a1;
    wv[2] = hi ? b2 : a2;
    wv[3] = hi ? b3 : a3;
    bf16x8 pfrag = __builtin_bit_cast(bf16x8, wv);
#pragma unroll
    for (int cp = 0; cp < 4; ++cp) {
      bf16x8 vfrag = *(const bf16x8*)(vbase + (size_t)(cp * 16 + lr) * SDIM + t * 32 + lg * 8);
      oacc[cp] = mf<C1>(vfrag, pfrag, oacc[cp]);   // row = dv, col = q
    }
  }
  // cross-wave reduce of O partials
  __shared__ float part[8][64][17];
#pragma unroll
  for (int cp = 0; cp < 4; ++cp)
#pragma unroll
    for (int rp = 0; rp < 4; ++rp)
      part[wid][cp * 16 + lg * 4 + rp][lr] = oacc[cp][rp];
  __syncthreads();
  {
    int qq = threadIdx.x >> 5;          // 0..15
    int dv = (threadIdx.x & 31) * 2;    // 0,2,..,62
    float s0 = 0.f, s1 = 0.f;
#pragma unroll
    for (int w = 0; w < 8; ++w) {
      s0 += part[w][dv][qq];
      s1 += part[w][dv + 1][qq];
    }
    unsigned ow = pack_bf16(s0, s1);
    *(unsigned*)(oh + ((size_t)(b * SDIM + q0 + qq)) * DDIM + h * DH + dv) = ow;
  }
}

__global__ __launch_bounds__(512, 2) void fused_kernel(const __bf16* __restrict__ qh,
                                                       const __bf16* __restrict__ kh,
                                                       const __bf16* __restrict__ vT,
                                                       const float* __restrict__ static_cov,
                                                       const int* __restrict__ mask,
                                                       const float* __restrict__ lam,
                                                       float* __restrict__ attn,
                                                       __bf16* __restrict__ oh,
                                                       const int* __restrict__ flag) {
  if (*flag == 1) fused_body<true>(qh, kh, vT, static_cov, mask, lam, attn, oh);
  else            fused_body<false>(qh, kh, vT, static_cov, mask, lam, attn, oh);
}

// ---- FC + residual: out = oh @ w_fc + q  (f32 out)
template <bool C1>
static __device__ __forceinline__ void fc_body(const __bf16* __restrict__ oh,
                                               const __bf16* __restrict__ wfcT,
                                               const float* __restrict__ resid,
                                               float* __restrict__ out) {
  int n0 = blockIdx.x * 64;
  int m0 = blockIdx.y * 64;
  int wid = threadIdx.x >> 6, lane = threadIdx.x & 63;
  int lr = lane & 15, lg = lane >> 4;
  int mrow = m0 + wid * 16;
  f32x4 acc[4] = {};
  for (int kb = 0; kb < DDIM; kb += 32) {
    bf16x8 afrag = *(const bf16x8*)(oh + (size_t)(mrow + lr) * DDIM + kb + lg * 8);
#pragma unroll
    for (int c = 0; c < 4; ++c) {
      bf16x8 bfrag = *(const bf16x8*)(wfcT + (size_t)(n0 + c * 16 + lr) * DDIM + kb + lg * 8);
      acc[c] = mf<C1>(afrag, bfrag, acc[c]);
    }
  }
#pragma unroll
  for (int c = 0; c < 4; ++c)
#pragma unroll
    for (int r = 0; r < 4; ++r) {
      size_t m = mrow + lg * 4 + r;
      size_t n = n0 + c * 16 + lr;
      float val = acc[c][r] + resid[m * DDIM + n];
      __builtin_nontemporal_store(val, out + m * DDIM + n);
    }
}

__global__ __launch_bounds__(256) void fc_kernel(const __bf16* __restrict__ oh,
                                                 const __bf16* __restrict__ wfcT,
                                                 const float* __restrict__ resid,
                                                 float* __restrict__ out,
                                                 const int* __restrict__ flag) {
  if (*flag == 1) fc_body<true>(oh, wfcT, resid, out);
  else            fc_body<false>(oh, wfcT, resid, out);
}

extern "C" void kernel_launch(void* const* d_in, const int* in_sizes, int n_in,
                              void* d_out, int out_size, void* d_ws, size_t ws_size,
                              hipStream_t stream) {
  const float* q = (const float*)d_in[0];
  const float* k = (const float*)d_in[1];
  const float* v = (const float*)d_in[2];
  const float* static_cov = (const float*)d_in[3];
  const int* mask = (const int*)d_in[4];
  const float* w_q = (const float*)d_in[5];
  const float* w_k = (const float*)d_in[6];
  const float* w_v = (const float*)d_in[7];
  const float* w_fc = (const float*)d_in[8];
  const float* lam = (const float*)d_in[9];
  const float* gamma = (const float*)d_in[10];
  const float* beta = (const float*)d_in[11];

  float* out = (float*)d_out;
  float* attn = out + (size_t)2 * SDIM * DDIM;

  char* ws = (char*)d_ws;
  const size_t MB4 = (size_t)4 << 20;
  __bf16* qn  = (__bf16*)(ws);
  __bf16* qh  = (__bf16*)(ws + 1 * MB4);
  __bf16* kh  = (__bf16*)(ws + 2 * MB4);
  __bf16* vT  = (__bf16*)(ws + 3 * MB4);
  __bf16* oh  = (__bf16*)(ws + 4 * MB4);
  __bf16* wqT = (__bf16*)(ws + 5 * MB4);
  __bf16* wkT = (__bf16*)(ws + 5 * MB4 + 524288);
  __bf16* wvT = (__bf16*)(ws + 5 * MB4 + 2 * 524288);
  __bf16* wfcT= (__bf16*)(ws + 5 * MB4 + 3 * 524288);
  int* flag   = (int*)(ws + 5 * MB4 + 4 * 524288);

  mfma_probe<<<dim3(1), dim3(64), 0, stream>>>(flag);
  ln_kernel<<<dim3(1024), dim3(256), 0, stream>>>(q, gamma, beta, qn);
  wtrans_kernel<<<dim3(1024, 4), dim3(256), 0, stream>>>(w_q, w_k, w_v, w_fc, wqT, wkT, wvT, wfcT);
  proj_kernel<<<dim3(8, 64, 3), dim3(256), 0, stream>>>(qn, k, v, wqT, wkT, wvT, lam, qh, kh, vT, flag);
  fused_kernel<<<dim3(16, 128), dim3(512), 0, stream>>>(qh, kh, vT, static_cov, mask, lam, attn, oh, flag);
  fc_kernel<<<dim3(8, 64), dim3(256), 0, stream>>>(oh, wfcT, q, out, flag);
}